// Round 5
// baseline (440.868 us; speedup 1.0000x reference)
//
#include <hip/hip_runtime.h>
#include <hip/hip_bf16.h>
#include <cstdint>
#include <cstddef>

// Problem constants (fixed by reference)
#define T_TOK 8192
#define DDIM  1024
#define FDIM  4096
#define NEXP  8
#define CAP   2048   // int(2.0 * T / E)

typedef __bf16 bf16_t;
typedef __bf16 bf16x8 __attribute__((ext_vector_type(8)));
typedef __bf16 bf16x4 __attribute__((ext_vector_type(4)));
typedef float  f32x4  __attribute__((ext_vector_type(4)));

// async global->LDS: lds dest must be WAVE-UNIFORM base; HW adds lane*16
__device__ __forceinline__ void gload16(const void* g, void* l) {
  __builtin_amdgcn_global_load_lds(
      (const __attribute__((address_space(1))) unsigned int*)g,
      (__attribute__((address_space(3))) unsigned int*)l,
      16, 0, 0);
}

#define VMWAIT(N) asm volatile("s_waitcnt vmcnt(" #N ")" ::: "memory")
#define BARR asm volatile("s_barrier" ::: "memory")

// ---------------- fused router: logits/softmax/argmax + x->bf16 + passthrough fill ----
__global__ void router_fused_kernel(const float* __restrict__ x, const float* __restrict__ wsw,
                                    const float* __restrict__ bsw, int* __restrict__ routes,
                                    float* __restrict__ rpm, float* __restrict__ partial,
                                    bf16_t* __restrict__ xbf, float* __restrict__ outf) {
  const int wv = threadIdx.x >> 6, lane = threadIdx.x & 63;
  const int t = blockIdx.x * 4 + wv;
  const float4* xr = (const float4*)(x + (size_t)t * DDIM);
  float4 xv[4];
  float a[8] = {0.f,0.f,0.f,0.f,0.f,0.f,0.f,0.f};
#pragma unroll
  for (int p = 0; p < 4; ++p) {
    xv[p] = xr[lane + p * 64];
#pragma unroll
    for (int j = 0; j < 4; ++j) {
      float v = ((const float*)&xv[p])[j];
      int d = (lane + p * 64) * 4 + j;
      const float4* wr = (const float4*)(wsw + d * 8);
      float4 w0 = wr[0], w1 = wr[1];
      a[0] += v * w0.x; a[1] += v * w0.y; a[2] += v * w0.z; a[3] += v * w0.w;
      a[4] += v * w1.x; a[5] += v * w1.y; a[6] += v * w1.z; a[7] += v * w1.w;
    }
  }
#pragma unroll
  for (int e = 0; e < 8; ++e) {
#pragma unroll
    for (int off = 32; off > 0; off >>= 1) a[e] += __shfl_xor(a[e], off);
    a[e] += bsw[e];
  }
  float m = a[0]; int arg = 0;
#pragma unroll
  for (int e = 1; e < 8; ++e) { if (a[e] > m) { m = a[e]; arg = e; } }
  float p8[8]; float s = 0.f;
#pragma unroll
  for (int e = 0; e < 8; ++e) { p8[e] = expf(a[e] - m); s += p8[e]; }
  float inv_s = 1.f / s;   // = softmax max since p[arg]=1
  // write bf16 tokens + passthrough output (overwritten later for kept tokens)
  bf16_t* xbr = xbf + (size_t)t * DDIM;
  float*  ofr = outf + (size_t)t * DDIM;
#pragma unroll
  for (int p = 0; p < 4; ++p) {
    int i4 = lane + p * 64;
    bf16x4 hb;
    hb[0] = (bf16_t)xv[p].x; hb[1] = (bf16_t)xv[p].y;
    hb[2] = (bf16_t)xv[p].z; hb[3] = (bf16_t)xv[p].w;
    *(bf16x4*)(xbr + (size_t)i4 * 4) = hb;
    float4 o = {xv[p].x * inv_s, xv[p].y * inv_s, xv[p].z * inv_s, xv[p].w * inv_s};
    ((float4*)ofr)[i4] = o;
  }
  __shared__ float pp[4][8];
  if (lane == 0) {
    routes[t] = arg;
    rpm[t] = inv_s;
#pragma unroll
    for (int e = 0; e < 8; ++e) pp[wv][e] = p8[e] * inv_s;
  }
  __syncthreads();
  if (threadIdx.x < 8) {
    int e = threadIdx.x;
    partial[(size_t)blockIdx.x * 8 + e] = pp[0][e] + pp[1][e] + pp[2][e] + pp[3][e];
  }
}

// ---------------- deterministic reduce of per-block prob sums ----------------
__global__ void reduce_partials_kernel(const float* __restrict__ partial,
                                       float* __restrict__ out_rps) {
  int tid = threadIdx.x;           // 256
  int e = tid & 7, j0 = tid >> 3;  // 32 lanes per expert
  float s = 0.f;
  for (int j = j0; j < 2048; j += 32) s += partial[j * 8 + e];
  __shared__ float red[256];
  red[tid] = s;
  __syncthreads();
  if (tid < 8) {
    float t = 0.f;
    for (int k = 0; k < 32; ++k) t += red[tid + 8 * k];
    out_rps[tid] = t;
  }
}

// ---------------- queue-position scan + dispatch index build ----------------
__global__ void scan_kernel(const int* __restrict__ routes, int* __restrict__ inv,
                            int* __restrict__ counts_i, float* __restrict__ out_counts,
                            float* __restrict__ out_ndrop) {
  __shared__ int scnt[256][8];
  __shared__ int raw[8];
  int tid = threadIdx.x;
  int myr[32];
  int cnt[8] = {0,0,0,0,0,0,0,0};
  int tbase = tid * 32;
  for (int i = 0; i < 32; ++i) { int r = routes[tbase + i]; myr[i] = r; cnt[r]++; }
#pragma unroll
  for (int e = 0; e < 8; ++e) scnt[tid][e] = cnt[e];
  __syncthreads();
  if (tid < 8) {
    int run = 0;
    for (int j = 0; j < 256; ++j) { int v = scnt[j][tid]; scnt[j][tid] = run; run += v; }
    raw[tid] = run;
  }
  __syncthreads();
  int base[8];
#pragma unroll
  for (int e = 0; e < 8; ++e) base[e] = scnt[tid][e];
  for (int i = 0; i < 32; ++i) {
    int r = myr[i];
    int p = base[r]++;
    if (p < CAP) inv[r * CAP + p] = tbase + i;
  }
  if (tid < 8) {
    int c = min(raw[tid], CAP);
    counts_i[tid] = c;
    out_counts[tid] = (float)c;
  }
  if (tid == 0) {
    int kept = 0;
    for (int e = 0; e < 8; ++e) kept += min(raw[e], CAP);
    *out_ndrop = (float)(T_TOK - kept);
  }
}

// ---------------- fused transpose+convert for W1 and W2 in one launch ----------------
// z in [0,nb): W1 expert e0+z  (R=1024, C=4096);  z in [nb,2nb): W2 expert e0+z-nb (R=4096, C=1024)
__global__ void transpose_both_kernel(const float* __restrict__ W1, const float* __restrict__ W2,
                                      bf16_t* __restrict__ W1T, bf16_t* __restrict__ W2T,
                                      int nb, int e0) {
  const int z = blockIdx.z;
  const float* s; bf16_t* d; int R, C, bx, by;
  if (z < nb) {
    s = W1 + (size_t)(e0 + z) * ((size_t)DDIM * FDIM);
    d = W1T + (size_t)z * ((size_t)DDIM * FDIM);
    R = DDIM; C = FDIM; bx = blockIdx.x * 64; by = blockIdx.y * 64;
  } else {
    s = W2 + (size_t)(e0 + z - nb) * ((size_t)FDIM * DDIM);
    d = W2T + (size_t)(z - nb) * ((size_t)FDIM * DDIM);
    R = FDIM; C = DDIM; bx = blockIdx.y * 64; by = blockIdx.x * 64;
  }
  __shared__ float tile[64][65];
  int c4 = (threadIdx.x & 15) * 4;
  int r0 = threadIdx.x >> 4;        // 16 rows per pass, 4 passes
#pragma unroll
  for (int p = 0; p < 4; ++p) {
    int r = r0 + p * 16;
    float4 v = *(const float4*)&s[(size_t)(by + r) * C + bx + c4];
    tile[r][c4] = v.x; tile[r][c4 + 1] = v.y; tile[r][c4 + 2] = v.z; tile[r][c4 + 3] = v.w;
  }
  __syncthreads();
  int r8 = (threadIdx.x & 7) * 8;
  int cw = threadIdx.x >> 3;        // 32 cols per pass, 2 passes
#pragma unroll
  for (int p = 0; p < 2; ++p) {
    int c = cw + p * 32;
    bf16x8 o;
#pragma unroll
    for (int j = 0; j < 8; ++j) o[j] = (bf16_t)tile[r8 + j][c];
    *(bf16x8*)&d[(size_t)(bx + c) * R + by + r8] = o;
  }
}

// ============ MFMA GEMM: 128x128 tile, 4 waves, BK=32, 8-phase, 4 blocks/CU ============
// D[m][c] = sum_k A[m][k]*B[c][k] (row-major K-contiguous). 4 waves = 2M x 2N;
// wave output 64x64 = 4x4 frags of 16x16. LDS 32KB static:
//   A: [2buf][2lh][64 rows][64B]  (lh = row bit5; unit = 4KB = 256 thr x 16B)
//   B: 16KB + [2buf][2nh][64 cols][64B] (nh = col bit5)
// Swizzle: granule slot j = kg ^ ((row>>1)&3) within 64B rows -> 2-way (free) on
// ds_read_b128; content pre-swizzled at the GLOBAL source (gload_lds writes linear).
// Iter (t0=2i buf0, t1 buf1): phases (nh,lh) = P1(0,0) P2(0,1) P3(1,1) P4(1,0) on buf0,
// P5-P8 same on buf1. A frags read once per tile at their lh phase, HELD in regs;
// B likewise (af[4], bv[4] live across phases). Stage exactly 1 unit/phase:
//   P1:A(t1,l1) P2:B(t1,n1) P3:B(t2,n0) P4:A(t2,l0)+VM(2)
//   P5:A(t2,l1) P6:B(t2,n1) P7:B(t3,n0) P8:A(t3,l0)+VM(2)
// All write-windows verified vs region read phases; VM(2)@P4 completes all of t1.
// Loop body contains NO other VMEM ops (vmcnt counts depend on it).
template <int KDIM, int MODE>
__launch_bounds__(256, 4)
__global__ void gemm4_kernel(const bf16_t* __restrict__ Abase, const bf16_t* __restrict__ Bbase,
                             const int* __restrict__ inv, const int* __restrict__ counts_i,
                             const float* __restrict__ bias_all, const float* __restrict__ rpm,
                             void* __restrict__ outp, int e0) {
  constexpr int MDIM = (MODE == 1) ? FDIM : DDIM;
  constexpr int NT = KDIM / 32;
  constexpr int NI = NT / 2;
  __shared__ __align__(16) char smem[32768];

  // T1: XCD-chunked bijective swizzle (nwg % 8 == 0 by construction)
  const int nx = gridDim.x, ny = gridDim.y;
  const int nwg = nx * ny * gridDim.z;
  const int flat = blockIdx.x + nx * (blockIdx.y + ny * blockIdx.z);
  const int nf = (flat & 7) * (nwg >> 3) + (flat >> 3);
  const int bx = nf % nx;
  const int tmp = nf / nx;
  const int by = tmp % ny, bz = tmp / ny;

  const int e = e0 + bz;
  const int cnt = counts_i[e];
  const int c0 = bx * 128;
  if (c0 >= cnt) return;                 // uniform early-exit before any barrier
  const int m0 = by * 128;

  const bf16_t* A = Abase + (size_t)bz * ((size_t)MDIM * KDIM);
  const float* bias = bias_all + (size_t)e * MDIM;

  const int tid = threadIdx.x, lane = tid & 63, w = tid >> 6;
  const int l15 = lane & 15, l4 = lane >> 4;
  const int wm = w >> 1, wn = w & 1;

  // ---- stage sources (pre-swizzled global addresses), 1 gload/thread/unit ----
  size_t aOff[2];
#pragma unroll
  for (int lh = 0; lh < 2; ++lh) {
    int cc = tid >> 2;
    int r = ((cc >> 5) << 6) | (lh << 5) | (cc & 31);
    int kg = (tid & 3) ^ ((r >> 1) & 3);
    aOff[lh] = (size_t)(m0 + r) * KDIM + kg * 8;
  }
  const bf16_t* bPtr[2];
#pragma unroll
  for (int nh = 0; nh < 2; ++nh) {
    int cc = tid >> 2;
    int c = ((cc >> 5) << 6) | (nh << 5) | (cc & 31);
    int kg = (tid & 3) ^ ((c >> 1) & 3);
    if (MODE == 1) {
      int tok = inv[e * CAP + c0 + c];   // pre-zeroed -> token 0 for empty slots
      bPtr[nh] = Bbase + (size_t)tok * KDIM + kg * 8;
    } else {
      bPtr[nh] = Bbase + (size_t)bz * ((size_t)CAP * KDIM) + (size_t)(c0 + c) * KDIM + kg * 8;
    }
  }

  // ---- swizzled read offsets (region + row + granule), buf added at use ----
  int aRd[4], bRd[4];
#pragma unroll
  for (int mi = 0; mi < 4; ++mi) {
    int r = wm * 64 + mi * 16 + l15;
    aRd[mi] = ((r >> 5) & 1) * 4096 + ((((r >> 6) << 5) | (r & 31)) * 64)
              + ((l4 ^ ((r >> 1) & 3)) << 4);
  }
#pragma unroll
  for (int nj = 0; nj < 4; ++nj) {
    int c = wn * 64 + nj * 16 + l15;
    bRd[nj] = 16384 + ((c >> 5) & 1) * 4096 + ((((c >> 6) << 5) | (c & 31)) * 64)
              + ((l4 ^ ((c >> 1) & 3)) << 4);
  }

  auto stageA = [&](int t, int lh) {
    gload16(A + aOff[lh] + t * 32, smem + (t & 1) * 8192 + lh * 4096 + w * 1024);
  };
  auto stageB = [&](int t, int nh) {
    gload16(bPtr[nh] + t * 32, smem + 16384 + (t & 1) * 8192 + nh * 4096 + w * 1024);
  };

  f32x4 acc[4][4];
#pragma unroll
  for (int i = 0; i < 4; ++i)
#pragma unroll
    for (int j = 0; j < 4; ++j) acc[i][j] = (f32x4){0.f, 0.f, 0.f, 0.f};
  bf16x8 af[4], bv[4];

#define PHASE(BUF, NH, LH, RDA, RDB, STAGE, WAITC)                              \
  {                                                                             \
    if (RDA) {                                                                  \
      af[2*(LH)]   = *(const bf16x8*)(smem + (BUF)*8192 + aRd[2*(LH)]);         \
      af[2*(LH)+1] = *(const bf16x8*)(smem + (BUF)*8192 + aRd[2*(LH)+1]);       \
    }                                                                           \
    if (RDB) {                                                                  \
      bv[2*(NH)]   = *(const bf16x8*)(smem + (BUF)*8192 + bRd[2*(NH)]);         \
      bv[2*(NH)+1] = *(const bf16x8*)(smem + (BUF)*8192 + bRd[2*(NH)+1]);       \
    }                                                                           \
    STAGE;                                                                      \
    WAITC;                                                                      \
    BARR;                                                                       \
    asm volatile("s_waitcnt lgkmcnt(0)" ::: "memory");                          \
    __builtin_amdgcn_sched_barrier(0);                                          \
    __builtin_amdgcn_s_setprio(1);                                              \
    _Pragma("unroll") for (int u = 0; u < 2; ++u)                               \
      _Pragma("unroll") for (int v = 0; v < 2; ++v)                             \
        acc[2*(LH)+u][2*(NH)+v] = __builtin_amdgcn_mfma_f32_16x16x32_bf16(      \
            af[2*(LH)+u], bv[2*(NH)+v], acc[2*(LH)+u][2*(NH)+v], 0, 0, 0);      \
    __builtin_amdgcn_s_setprio(0);                                              \
    BARR;                                                                       \
  }

  // ---- prologue: t0 fully + {B(t1,n0), A(t1,l0)} outstanding (= steady invariant) ----
  stageA(0, 0); stageA(0, 1); stageB(0, 0); stageB(0, 1);
  stageB(1, 0); stageA(1, 0);
  VMWAIT(2);
  BARR;

  for (int i = 0; i < NI - 1; ++i) {
    const int t1 = 2 * i + 1, t2 = 2 * i + 2, t3 = 2 * i + 3;
    PHASE(0, 0, 0, 1, 1, { stageA(t1, 1); }, {});
    PHASE(0, 0, 1, 1, 0, { stageB(t1, 1); }, {});
    PHASE(0, 1, 1, 0, 1, { stageB(t2, 0); }, {});
    PHASE(0, 1, 0, 0, 0, { stageA(t2, 0); }, { VMWAIT(2); });
    PHASE(1, 0, 0, 1, 1, { stageA(t2, 1); }, {});
    PHASE(1, 0, 1, 1, 0, { stageB(t2, 1); }, {});
    PHASE(1, 1, 1, 0, 1, { stageB(t3, 0); }, {});
    PHASE(1, 1, 0, 0, 0, { stageA(t3, 0); }, { VMWAIT(2); });
  }
  {  // last iter: t1 = NT-1; no t2/t3
    const int t1 = NT - 1;
    PHASE(0, 0, 0, 1, 1, { stageA(t1, 1); }, {});
    PHASE(0, 0, 1, 1, 0, { stageB(t1, 1); }, {});
    PHASE(0, 1, 1, 0, 1, {}, {});
    PHASE(0, 1, 0, 0, 0, {}, { VMWAIT(0); });
    PHASE(1, 0, 0, 1, 1, {}, {});
    PHASE(1, 0, 1, 1, 0, {}, {});
    PHASE(1, 1, 1, 0, 1, {}, {});
    PHASE(1, 1, 0, 0, 0, {}, {});
  }
#undef PHASE

  // ---- epilogue: D layout col=lane&15, row=(lane>>4)*4+reg [verified m89/m91] ----
  if constexpr (MODE == 1) {
    bf16_t* h = (bf16_t*)outp + (size_t)bz * ((size_t)CAP * FDIM);
#pragma unroll
    for (int nj = 0; nj < 4; ++nj) {
      int c = c0 + wn * 64 + nj * 16 + l15;
      bf16_t* hrow = h + (size_t)c * FDIM;
#pragma unroll
      for (int mi = 0; mi < 4; ++mi) {
        int f = m0 + wm * 64 + mi * 16 + l4 * 4;
        const float4 bi = *(const float4*)&bias[f];
        f32x4 v = acc[mi][nj];
        bf16x4 hv;
        hv[0] = (bf16_t)fmaxf(v[0] + bi.x, 0.f);
        hv[1] = (bf16_t)fmaxf(v[1] + bi.y, 0.f);
        hv[2] = (bf16_t)fmaxf(v[2] + bi.z, 0.f);
        hv[3] = (bf16_t)fmaxf(v[3] + bi.w, 0.f);
        *(bf16x4*)&hrow[f] = hv;
      }
    }
  } else {
    float* finalp = (float*)outp;
#pragma unroll
    for (int nj = 0; nj < 4; ++nj) {
      int c = c0 + wn * 64 + nj * 16 + l15;
      if (c < cnt) {
        int tok = inv[e * CAP + c];
        float r = rpm[tok];
        float* orow = finalp + (size_t)tok * DDIM;
#pragma unroll
        for (int mi = 0; mi < 4; ++mi) {
          int d = m0 + wm * 64 + mi * 16 + l4 * 4;
          const float4 bi = *(const float4*)&bias[d];
          f32x4 v = acc[mi][nj];
          float4 o;
          o.x = (v[0] + bi.x) * r;
          o.y = (v[1] + bi.y) * r;
          o.z = (v[2] + bi.z) * r;
          o.w = (v[3] + bi.w) * r;
          *(float4*)&orow[d] = o;
        }
      }
    }
  }
}

// ---------------- host launcher ----------------
extern "C" void kernel_launch(void* const* d_in, const int* in_sizes, int n_in,
                              void* d_out, int out_size, void* d_ws, size_t ws_size,
                              hipStream_t stream) {
  (void)in_sizes; (void)n_in; (void)out_size;
  const float* x   = (const float*)d_in[0];
  const float* wsw = (const float*)d_in[1];
  const float* bsw = (const float*)d_in[2];
  const float* W1  = (const float*)d_in[3];
  const float* b1  = (const float*)d_in[4];
  const float* W2  = (const float*)d_in[5];
  const float* b2  = (const float*)d_in[6];

  float* out_final  = (float*)d_out;            // [T][D]
  float* out_counts = out_final + 8388608;      // [8]
  float* out_rps    = out_final + 8388616;      // [8]
  float* out_ndrop  = out_final + 8388624;      // [1]
  float* out_rpm    = out_final + 8388625;      // [T]

  char* ws = (char*)d_ws;
  size_t off = 0;
  auto carve = [&](size_t bytes) {
    char* p = ws + off;
    off += (bytes + 255) & ~(size_t)255;
    return p;
  };
  bf16_t* xbf     = (bf16_t*)carve((size_t)T_TOK * DDIM * 2);   // 16 MB
  int*    routes  = (int*)   carve((size_t)T_TOK * 4);
  int*    inv     = (int*)   carve((size_t)NEXP * CAP * 4);
  int*    counts_i= (int*)   carve((size_t)NEXP * 4);
  float*  partial = (float*) carve((size_t)2048 * 8 * 4);
  size_t fixed = off;
  const size_t PER_E = 2 * (size_t)FDIM * DDIM * 2 + (size_t)CAP * FDIM * 2; // W1T+W2T+h = 32MB
  int nb = 8;
  while (nb > 1 && fixed + (size_t)nb * PER_E > ws_size) nb >>= 1;
  bf16_t* W1T  = (bf16_t*)carve((size_t)nb * FDIM * DDIM * 2);
  bf16_t* W2T  = (bf16_t*)carve((size_t)nb * DDIM * FDIM * 2);
  bf16_t* hbuf = (bf16_t*)carve((size_t)nb * CAP * FDIM * 2);

  router_fused_kernel<<<T_TOK / 4, 256, 0, stream>>>(x, wsw, bsw, routes, out_rpm,
                                                     partial, xbf, out_final);
  reduce_partials_kernel<<<1, 256, 0, stream>>>(partial, out_rps);
  hipMemsetAsync(inv, 0, (size_t)NEXP * CAP * 4, stream);
  scan_kernel<<<1, 256, 0, stream>>>(routes, inv, counts_i, out_counts, out_ndrop);

  for (int e0 = 0; e0 < NEXP; e0 += nb) {
    transpose_both_kernel<<<dim3(64, 16, 2 * nb), 256, 0, stream>>>(W1, W2, W1T, W2T, nb, e0);
    gemm4_kernel<DDIM, 1><<<dim3(CAP / 128, FDIM / 128, nb), 256, 0, stream>>>(
        W1T, xbf, inv, counts_i, b1, nullptr, hbuf, e0);
    gemm4_kernel<FDIM, 2><<<dim3(CAP / 128, DDIM / 128, nb), 256, 0, stream>>>(
        W2T, hbuf, inv, counts_i, b2, out_rpm, d_out, e0);
  }
}